// Round 5
// baseline (240.852 us; speedup 1.0000x reference)
//
#include <hip/hip_runtime.h>
#include <hip/hip_fp16.h>

#define HH 1024
#define WW 1024
#define NN 12
#define HWSZ (HH * WW)
#define SW 88                 // staged box width in texels (even, 16B-chunkable)
#define SH 46                 // staged box rows
#define NCH (SH * (SW / 2))   // 16B chunks to stage = 46*44 = 2024

typedef float  floatx4 __attribute__((ext_vector_type(4)));
typedef unsigned int u32x4 __attribute__((ext_vector_type(4)));

__device__ __forceinline__ float2 h2f(unsigned int u) {
    __half2 h = *(__half2*)&u;
    return __half22float2(h);
}

// ---------- prepass: planar fp32 (3,H,W) -> packed (H,W) half4 {rg, b0} ----------
__global__ __launch_bounds__(256) void pack_kernel(const float* __restrict__ x,
                                                   uint2* __restrict__ xp) {
    int i = (blockIdx.x * 256 + threadIdx.x) * 4;
    float4 r = *(const float4*)(x + i);
    float4 g = *(const float4*)(x + i + HWSZ);
    float4 b = *(const float4*)(x + i + 2 * HWSZ);

    __half2 rg0 = __float22half2_rn(make_float2(r.x, g.x));
    __half2 rg1 = __float22half2_rn(make_float2(r.y, g.y));
    __half2 rg2 = __float22half2_rn(make_float2(r.z, g.z));
    __half2 rg3 = __float22half2_rn(make_float2(r.w, g.w));
    __half2 b0  = __float22half2_rn(make_float2(b.x, 0.f));
    __half2 b1  = __float22half2_rn(make_float2(b.y, 0.f));
    __half2 b2  = __float22half2_rn(make_float2(b.z, 0.f));
    __half2 b3  = __float22half2_rn(make_float2(b.w, 0.f));

    u32x4 v0 = { *(unsigned*)&rg0, *(unsigned*)&b0, *(unsigned*)&rg1, *(unsigned*)&b1 };
    u32x4 v1 = { *(unsigned*)&rg2, *(unsigned*)&b2, *(unsigned*)&rg3, *(unsigned*)&b3 };
    u32x4* dst = (u32x4*)(xp + i);
    dst[0] = v0;
    dst[1] = v1;
}

// ---------- main: LDS-staged input footprint, 64x16 tile, 4 px/thread ----------
__global__ __launch_bounds__(256) void warp_lds_kernel(
    const uint2* __restrict__ xp,     // (H, W) half4 texels
    const float* __restrict__ theta,  // (12, 2, 3)
    float* __restrict__ xs,           // (12, 3, H, W)
    float* __restrict__ os)           // (12, H, W)
{
    __shared__ uint2 sm[SH * SW];     // 32384 B

    int m = blockIdx.z;
    const float* t = theta + m * 6;   // block-uniform
    float t00 = t[0], t01 = t[1], t02 = t[2];
    float t10 = t[3], t11 = t[4], t12 = t[5];

    int wbase = blockIdx.x * 64;
    int hbase = blockIdx.y * 16;

    // ---- input-space bounding box from the 4 tile-corner pixel centers ----
    float gxl = (wbase + 0.5f)  * (2.0f / WW) - 1.0f;
    float gxh = (wbase + 63.5f) * (2.0f / WW) - 1.0f;
    float gyl = (hbase + 0.5f)  * (2.0f / HH) - 1.0f;
    float gyh = (hbase + 15.5f) * (2.0f / HH) - 1.0f;

    float u_ll = t00 * gxl + t01 * gyl + t02;
    float u_lh = t00 * gxl + t01 * gyh + t02;
    float u_hl = t00 * gxh + t01 * gyl + t02;
    float u_hh = t00 * gxh + t01 * gyh + t02;
    float v_ll = t10 * gxl + t11 * gyl + t12;
    float v_lh = t10 * gxl + t11 * gyh + t12;
    float v_hl = t10 * gxh + t11 * gyl + t12;
    float v_hh = t10 * gxh + t11 * gyh + t12;

    float umin = fminf(fminf(u_ll, u_lh), fminf(u_hl, u_hh));
    float vmin = fminf(fminf(v_ll, v_lh), fminf(v_hl, v_hh));
    float ixmin = ((umin + 1.0f) * WW - 1.0f) * 0.5f;
    float iymin = ((vmin + 1.0f) * HH - 1.0f) * 0.5f;

    int x_lo = (int)floorf(ixmin) - 1;
    int y_lo = (int)floorf(iymin) - 1;
    int x_s = (min(max(x_lo, 0), WW - SW)) & ~1;   // even for 16B alignment
    int y_s = min(max(y_lo, 0), HH - SH);

    // ---- stage SHxSW texel box, coalesced 16B chunks ----
    const uint2* src0 = xp + (size_t)y_s * WW + x_s;
    for (int c = threadIdx.x; c < NCH; c += 256) {
        int r   = c / (SW / 2);
        int col = c - r * (SW / 2);
        u32x4 v = *(const u32x4*)(src0 + (size_t)r * WW + col * 2);
        *(u32x4*)(&sm[r * SW + col * 2]) = v;
    }
    __syncthreads();

    // ---- per-pixel bilinear from LDS ----
    int wl = threadIdx.x & 15;
    int hl = threadIdx.x >> 4;
    int w4 = wbase + wl * 4;
    int h  = hbase + hl;

    float gx0 = (w4 + 0.5f) * (2.0f / WW) - 1.0f;
    float gy  = (h  + 0.5f) * (2.0f / HH) - 1.0f;
    float ix0 = ((t00 * gx0 + t01 * gy + t02 + 1.0f) * WW - 1.0f) * 0.5f;
    float iy0 = ((t10 * gx0 + t11 * gy + t12 + 1.0f) * HH - 1.0f) * 0.5f;
    // per-pixel step in input space: d(ix)/d(w)=t00, d(iy)/d(w)=t10

    float r0[4], r1[4], r2[4], ro[4];

    #pragma unroll
    for (int j = 0; j < 4; ++j) {
        float ix = ix0 + (float)j * t00;
        float iy = iy0 + (float)j * t10;

        float xf = floorf(ix), yf = floorf(iy);
        int x0 = (int)xf, y0 = (int)yf;
        int x1 = x0 + 1,  y1 = y0 + 1;
        float fx = ix - xf, fy = iy - yf;
        float wx0 = 1.0f - fx, wx1 = fx;
        float wy0 = 1.0f - fy, wy1 = fy;

        bool vx0 = (unsigned)x0 < WW;
        bool vx1 = (unsigned)x1 < WW;
        bool vy0 = (unsigned)y0 < HH;
        bool vy1 = (unsigned)y1 < HH;

        int lx0 = min(max(x0 - x_s, 0), SW - 1);
        int lx1 = min(max(x1 - x_s, 0), SW - 1);
        int ly0 = min(max(y0 - y_s, 0), SH - 1);
        int ly1 = min(max(y1 - y_s, 0), SH - 1);

        uint2 q00 = sm[ly0 * SW + lx0];
        uint2 q10 = sm[ly0 * SW + lx1];
        uint2 q01 = sm[ly1 * SW + lx0];
        uint2 q11 = sm[ly1 * SW + lx1];

        float w00 = wx0 * wy0 * ((vx0 & vy0) ? 1.0f : 0.0f);
        float w10 = wx1 * wy0 * ((vx1 & vy0) ? 1.0f : 0.0f);
        float w01 = wx0 * wy1 * ((vx0 & vy1) ? 1.0f : 0.0f);
        float w11 = wx1 * wy1 * ((vx1 & vy1) ? 1.0f : 0.0f);

        float2 c00 = h2f(q00.x), c10 = h2f(q10.x), c01 = h2f(q01.x), c11 = h2f(q11.x);
        float  b00 = h2f(q00.y).x, b10 = h2f(q10.y).x, b01 = h2f(q01.y).x, b11 = h2f(q11.y).x;

        r0[j] = fmaf(w00, c00.x, fmaf(w10, c10.x, fmaf(w01, c01.x, w11 * c11.x)));
        r1[j] = fmaf(w00, c00.y, fmaf(w10, c10.y, fmaf(w01, c01.y, w11 * c11.y)));
        r2[j] = fmaf(w00, b00,   fmaf(w10, b10,   fmaf(w01, b01,   w11 * b11)));
        ro[j] = w00 + w10 + w01 + w11;
    }

    int pix = h * WW + w4;
    floatx4* o0 = (floatx4*)(xs + ((size_t)(m * 3 + 0)) * HWSZ + pix);
    floatx4* o1 = (floatx4*)(xs + ((size_t)(m * 3 + 1)) * HWSZ + pix);
    floatx4* o2 = (floatx4*)(xs + ((size_t)(m * 3 + 2)) * HWSZ + pix);
    floatx4* oo = (floatx4*)(os + (size_t)m * HWSZ + pix);
    floatx4 s0 = {r0[0], r0[1], r0[2], r0[3]};
    floatx4 s1 = {r1[0], r1[1], r1[2], r1[3]};
    floatx4 s2 = {r2[0], r2[1], r2[2], r2[3]};
    floatx4 so = {ro[0], ro[1], ro[2], ro[3]};
    __builtin_nontemporal_store(s0, o0);
    __builtin_nontemporal_store(s1, o1);
    __builtin_nontemporal_store(s2, o2);
    __builtin_nontemporal_store(so, oo);
}

// ---------- fallback (R1 kernel) if ws too small ----------
__global__ __launch_bounds__(256) void warp_kernel(
    const float* __restrict__ x, const float* __restrict__ theta,
    float* __restrict__ xs, float* __restrict__ os)
{
    int idx = blockIdx.x * blockDim.x + threadIdx.x;
    if (idx >= NN * HWSZ) return;
    int m = idx >> 20;
    int h = (idx >> 10) & (HH - 1);
    int w = idx & (WW - 1);
    const float* t = theta + m * 6;
    float t00 = t[0], t01 = t[1], t02 = t[2];
    float t10 = t[3], t11 = t[4], t12 = t[5];
    float gx = (w + 0.5f) * (2.0f / WW) - 1.0f;
    float gy = (h + 0.5f) * (2.0f / HH) - 1.0f;
    float u = t00 * gx + t01 * gy + t02;
    float v = t10 * gx + t11 * gy + t12;
    float ix = ((u + 1.0f) * WW - 1.0f) * 0.5f;
    float iy = ((v + 1.0f) * HH - 1.0f) * 0.5f;
    float x0f = floorf(ix), y0f = floorf(iy);
    int x0 = (int)x0f, y0 = (int)y0f;
    int x1 = x0 + 1, y1 = y0 + 1;
    float fx = ix - x0f, fy = iy - y0f;
    float wx0 = 1.0f - fx, wx1 = fx, wy0 = 1.0f - fy, wy1 = fy;
    bool vx0 = (x0 >= 0) & (x0 < WW), vx1 = (x1 >= 0) & (x1 < WW);
    bool vy0 = (y0 >= 0) & (y0 < HH), vy1 = (y1 >= 0) & (y1 < HH);
    int cx0 = min(max(x0, 0), WW - 1), cx1 = min(max(x1, 0), WW - 1);
    int cy0 = min(max(y0, 0), HH - 1), cy1 = min(max(y1, 0), HH - 1);
    float w00 = wx0 * wy0 * ((vx0 & vy0) ? 1.0f : 0.0f);
    float w10 = wx1 * wy0 * ((vx1 & vy0) ? 1.0f : 0.0f);
    float w01 = wx0 * wy1 * ((vx0 & vy1) ? 1.0f : 0.0f);
    float w11 = wx1 * wy1 * ((vx1 & vy1) ? 1.0f : 0.0f);
    int i00 = cy0 * WW + cx0, i10 = cy0 * WW + cx1;
    int i01 = cy1 * WW + cx0, i11 = cy1 * WW + cx1;
    int pix = h * WW + w;
    #pragma unroll
    for (int c = 0; c < 3; ++c) {
        const float* p = x + c * HWSZ;
        float val = w00 * p[i00] + w10 * p[i10] + w01 * p[i01] + w11 * p[i11];
        xs[(m * 3 + c) * HWSZ + pix] = val;
    }
    os[m * HWSZ + pix] = w00 + w10 + w01 + w11;
}

__global__ void tail_kernel(const float* __restrict__ theta,
                            float* __restrict__ zout,
                            float* __restrict__ izout)
{
    int m = threadIdx.x;
    if (m >= NN) return;
    const float* t = theta + m * 6;
    float a = t[0], b = t[1], tx = t[2];
    float c = t[3], d = t[4], ty = t[5];
    #pragma unroll
    for (int i = 0; i < 6; ++i) zout[m * 6 + i] = t[i];
    float det = a * d - b * c;
    float id = 1.0f / det;
    float ia = d * id, ib = -b * id, ic = -c * id, idd = a * id;
    float itx = -(ia * tx + ib * ty);
    float ity = -(ic * tx + idd * ty);
    izout[m * 6 + 0] = ia;  izout[m * 6 + 1] = ib;  izout[m * 6 + 2] = itx;
    izout[m * 6 + 3] = ic;  izout[m * 6 + 4] = idd; izout[m * 6 + 5] = ity;
}

extern "C" void kernel_launch(void* const* d_in, const int* in_sizes, int n_in,
                              void* d_out, int out_size, void* d_ws, size_t ws_size,
                              hipStream_t stream) {
    const float* x     = (const float*)d_in[0];   // (1,3,1024,1024)
    const float* theta = (const float*)d_in[1];   // (1,12,2,3)

    float* out = (float*)d_out;
    float* xs  = out;
    float* os  = xs + (size_t)NN * 3 * HWSZ;
    float* z   = os + (size_t)NN * HWSZ;
    float* iz  = z + NN * 6;

    if (ws_size >= (size_t)HWSZ * sizeof(uint2)) {
        uint2* xp = (uint2*)d_ws;
        pack_kernel<<<HWSZ / 4 / 256, 256, 0, stream>>>(x, xp);
        dim3 grid(WW / 64, HH / 16, NN);
        warp_lds_kernel<<<grid, 256, 0, stream>>>(xp, theta, xs, os);
    } else {
        int total = NN * HWSZ;
        warp_kernel<<<(total + 255) / 256, 256, 0, stream>>>(x, theta, xs, os);
    }
    tail_kernel<<<1, 64, 0, stream>>>(theta, z, iz);
}

// Round 6
// 218.634 us; speedup vs baseline: 1.1016x; 1.1016x over previous
//
#include <hip/hip_runtime.h>
#include <hip/hip_fp16.h>

#define HH 1024
#define WW 1024
#define NN 12
#define HWSZ (HH * WW)

typedef float  floatx4 __attribute__((ext_vector_type(4)));
typedef unsigned int u32x4 __attribute__((ext_vector_type(4)));

// 16B of texel data (2 adjacent 8B fp16 texels), only 8B-aligned.
struct __attribute__((packed, aligned(8))) pair16 { u32x4 v; };

__device__ __forceinline__ float2 h2f(unsigned int u) {
    __half2 h = *(__half2*)&u;
    return __half22float2(h);
}

// ---------- prepass: planar fp32 (3,H,W) -> packed (H,W) half4 {rg, b0} ----------
__global__ __launch_bounds__(256) void pack_kernel(const float* __restrict__ x,
                                                   uint2* __restrict__ xp) {
    int i = (blockIdx.x * 256 + threadIdx.x) * 4;
    float4 r = *(const float4*)(x + i);
    float4 g = *(const float4*)(x + i + HWSZ);
    float4 b = *(const float4*)(x + i + 2 * HWSZ);

    __half2 rg0 = __float22half2_rn(make_float2(r.x, g.x));
    __half2 rg1 = __float22half2_rn(make_float2(r.y, g.y));
    __half2 rg2 = __float22half2_rn(make_float2(r.z, g.z));
    __half2 rg3 = __float22half2_rn(make_float2(r.w, g.w));
    __half2 b0  = __float22half2_rn(make_float2(b.x, 0.f));
    __half2 b1  = __float22half2_rn(make_float2(b.y, 0.f));
    __half2 b2  = __float22half2_rn(make_float2(b.z, 0.f));
    __half2 b3  = __float22half2_rn(make_float2(b.w, 0.f));

    u32x4 v0 = { *(unsigned*)&rg0, *(unsigned*)&b0, *(unsigned*)&rg1, *(unsigned*)&b1 };
    u32x4 v1 = { *(unsigned*)&rg2, *(unsigned*)&b2, *(unsigned*)&rg3, *(unsigned*)&b3 };
    u32x4* dst = (u32x4*)(xp + i);
    dst[0] = v0;
    dst[1] = v1;
}

// ---------- main: 32x8 wave tile (32x32 block), 4 px/thread, phase-split loads ----------
__global__ __launch_bounds__(256) void warp_tile_kernel(
    const uint2* __restrict__ xp,     // (H, W) half4 texels
    const float* __restrict__ theta,  // (12, 2, 3)
    float* __restrict__ xs,           // (12, 3, H, W)
    float* __restrict__ os)           // (12, H, W)
{
    int wl = threadIdx.x & 7;         // 8 w-groups -> 32 px wide per wave
    int hl = threadIdx.x >> 3;        // 32 rows per block (8 rows per wave)
    int w4 = (blockIdx.x * 8 + wl) * 4;
    int h  = blockIdx.y * 32 + hl;
    int m  = blockIdx.z;

    const float* t = theta + m * 6;   // block-uniform -> scalar loads
    float t00 = t[0], t01 = t[1], t02 = t[2];
    float t10 = t[3], t11 = t[4], t12 = t[5];

    float gx0 = (w4 + 0.5f) * (2.0f / WW) - 1.0f;
    float gy  = (h  + 0.5f) * (2.0f / HH) - 1.0f;
    float ix0 = ((t00 * gx0 + t01 * gy + t02 + 1.0f) * WW - 1.0f) * 0.5f;
    float iy0 = ((t10 * gx0 + t11 * gy + t12 + 1.0f) * HH - 1.0f) * 0.5f;
    // per-pixel step: d(ix)/d(w)=t00, d(iy)/d(w)=t10

    // ---- phase 1: addresses + weight terms + issue all 8 loads ----
    u32x4 P0[4], P1[4];
    float w00a[4], w10a[4], w01a[4], w11a[4];
    bool  lo0a[4], lo1a[4];

    #pragma unroll
    for (int j = 0; j < 4; ++j) {
        float ix = ix0 + (float)j * t00;
        float iy = iy0 + (float)j * t10;

        float xf = floorf(ix), yf = floorf(iy);
        int x0 = (int)xf, y0 = (int)yf;
        int x1 = x0 + 1,  y1 = y0 + 1;
        float fx = ix - xf, fy = iy - yf;
        float wx0 = 1.0f - fx, wx1 = fx;
        float wy0 = 1.0f - fy, wy1 = fy;

        bool vx0 = (unsigned)x0 < WW;
        bool vx1 = (unsigned)x1 < WW;
        bool vy0 = (unsigned)y0 < HH;
        bool vy1 = (unsigned)y1 < HH;

        int bx  = min(max(x0, 0), WW - 2);       // pair base column
        int cx0 = min(max(x0, 0), WW - 1);
        int cx1 = min(max(x1, 0), WW - 1);
        int by0 = min(max(y0, 0), HH - 1);
        int by1 = min(max(y1, 0), HH - 1);

        P0[j] = ((const pair16*)(xp + by0 * WW + bx))->v;  // row y0: texels bx,bx+1
        P1[j] = ((const pair16*)(xp + by1 * WW + bx))->v;  // row y1

        lo0a[j] = (cx0 == bx);
        lo1a[j] = (cx1 == bx);
        w00a[j] = wx0 * wy0 * ((vx0 & vy0) ? 1.0f : 0.0f);
        w10a[j] = wx1 * wy0 * ((vx1 & vy0) ? 1.0f : 0.0f);
        w01a[j] = wx0 * wy1 * ((vx0 & vy1) ? 1.0f : 0.0f);
        w11a[j] = wx1 * wy1 * ((vx1 & vy1) ? 1.0f : 0.0f);
    }

    // ---- phase 2: select + blend ----
    float r0[4], r1[4], r2[4], ro[4];
    #pragma unroll
    for (int j = 0; j < 4; ++j) {
        bool lo0 = lo0a[j], lo1 = lo1a[j];
        u32x4 p0 = P0[j], p1 = P1[j];
        unsigned rg00 = lo0 ? p0.x : p0.z,  bb00 = lo0 ? p0.y : p0.w;
        unsigned rg10 = lo1 ? p0.x : p0.z,  bb10 = lo1 ? p0.y : p0.w;
        unsigned rg01 = lo0 ? p1.x : p1.z,  bb01 = lo0 ? p1.y : p1.w;
        unsigned rg11 = lo1 ? p1.x : p1.z,  bb11 = lo1 ? p1.y : p1.w;

        float w00 = w00a[j], w10 = w10a[j], w01 = w01a[j], w11 = w11a[j];

        float2 c00 = h2f(rg00), c10 = h2f(rg10), c01 = h2f(rg01), c11 = h2f(rg11);
        float  b00 = h2f(bb00).x, b10 = h2f(bb10).x, b01 = h2f(bb01).x, b11 = h2f(bb11).x;

        r0[j] = fmaf(w00, c00.x, fmaf(w10, c10.x, fmaf(w01, c01.x, w11 * c11.x)));
        r1[j] = fmaf(w00, c00.y, fmaf(w10, c10.y, fmaf(w01, c01.y, w11 * c11.y)));
        r2[j] = fmaf(w00, b00,   fmaf(w10, b10,   fmaf(w01, b01,   w11 * b11)));
        ro[j] = w00 + w10 + w01 + w11;
    }

    int pix = h * WW + w4;
    floatx4* o0 = (floatx4*)(xs + ((size_t)(m * 3 + 0)) * HWSZ + pix);
    floatx4* o1 = (floatx4*)(xs + ((size_t)(m * 3 + 1)) * HWSZ + pix);
    floatx4* o2 = (floatx4*)(xs + ((size_t)(m * 3 + 2)) * HWSZ + pix);
    floatx4* oo = (floatx4*)(os + (size_t)m * HWSZ + pix);
    floatx4 s0 = {r0[0], r0[1], r0[2], r0[3]};
    floatx4 s1 = {r1[0], r1[1], r1[2], r1[3]};
    floatx4 s2 = {r2[0], r2[1], r2[2], r2[3]};
    floatx4 so = {ro[0], ro[1], ro[2], ro[3]};
    __builtin_nontemporal_store(s0, o0);
    __builtin_nontemporal_store(s1, o1);
    __builtin_nontemporal_store(s2, o2);
    __builtin_nontemporal_store(so, oo);
}

// ---------- fallback (R1 kernel) if ws too small ----------
__global__ __launch_bounds__(256) void warp_kernel(
    const float* __restrict__ x, const float* __restrict__ theta,
    float* __restrict__ xs, float* __restrict__ os)
{
    int idx = blockIdx.x * blockDim.x + threadIdx.x;
    if (idx >= NN * HWSZ) return;
    int m = idx >> 20;
    int h = (idx >> 10) & (HH - 1);
    int w = idx & (WW - 1);
    const float* t = theta + m * 6;
    float t00 = t[0], t01 = t[1], t02 = t[2];
    float t10 = t[3], t11 = t[4], t12 = t[5];
    float gx = (w + 0.5f) * (2.0f / WW) - 1.0f;
    float gy = (h + 0.5f) * (2.0f / HH) - 1.0f;
    float u = t00 * gx + t01 * gy + t02;
    float v = t10 * gx + t11 * gy + t12;
    float ix = ((u + 1.0f) * WW - 1.0f) * 0.5f;
    float iy = ((v + 1.0f) * HH - 1.0f) * 0.5f;
    float x0f = floorf(ix), y0f = floorf(iy);
    int x0 = (int)x0f, y0 = (int)y0f;
    int x1 = x0 + 1, y1 = y0 + 1;
    float fx = ix - x0f, fy = iy - y0f;
    float wx0 = 1.0f - fx, wx1 = fx, wy0 = 1.0f - fy, wy1 = fy;
    bool vx0 = (x0 >= 0) & (x0 < WW), vx1 = (x1 >= 0) & (x1 < WW);
    bool vy0 = (y0 >= 0) & (y0 < HH), vy1 = (y1 >= 0) & (y1 < HH);
    int cx0 = min(max(x0, 0), WW - 1), cx1 = min(max(x1, 0), WW - 1);
    int cy0 = min(max(y0, 0), HH - 1), cy1 = min(max(y1, 0), HH - 1);
    float w00 = wx0 * wy0 * ((vx0 & vy0) ? 1.0f : 0.0f);
    float w10 = wx1 * wy0 * ((vx1 & vy0) ? 1.0f : 0.0f);
    float w01 = wx0 * wy1 * ((vx0 & vy1) ? 1.0f : 0.0f);
    float w11 = wx1 * wy1 * ((vx1 & vy1) ? 1.0f : 0.0f);
    int i00 = cy0 * WW + cx0, i10 = cy0 * WW + cx1;
    int i01 = cy1 * WW + cx0, i11 = cy1 * WW + cx1;
    int pix = h * WW + w;
    #pragma unroll
    for (int c = 0; c < 3; ++c) {
        const float* p = x + c * HWSZ;
        float val = w00 * p[i00] + w10 * p[i10] + w01 * p[i01] + w11 * p[i11];
        xs[(m * 3 + c) * HWSZ + pix] = val;
    }
    os[m * HWSZ + pix] = w00 + w10 + w01 + w11;
}

__global__ void tail_kernel(const float* __restrict__ theta,
                            float* __restrict__ zout,
                            float* __restrict__ izout)
{
    int m = threadIdx.x;
    if (m >= NN) return;
    const float* t = theta + m * 6;
    float a = t[0], b = t[1], tx = t[2];
    float c = t[3], d = t[4], ty = t[5];
    #pragma unroll
    for (int i = 0; i < 6; ++i) zout[m * 6 + i] = t[i];
    float det = a * d - b * c;
    float id = 1.0f / det;
    float ia = d * id, ib = -b * id, ic = -c * id, idd = a * id;
    float itx = -(ia * tx + ib * ty);
    float ity = -(ic * tx + idd * ty);
    izout[m * 6 + 0] = ia;  izout[m * 6 + 1] = ib;  izout[m * 6 + 2] = itx;
    izout[m * 6 + 3] = ic;  izout[m * 6 + 4] = idd; izout[m * 6 + 5] = ity;
}

extern "C" void kernel_launch(void* const* d_in, const int* in_sizes, int n_in,
                              void* d_out, int out_size, void* d_ws, size_t ws_size,
                              hipStream_t stream) {
    const float* x     = (const float*)d_in[0];   // (1,3,1024,1024)
    const float* theta = (const float*)d_in[1];   // (1,12,2,3)

    float* out = (float*)d_out;
    float* xs  = out;
    float* os  = xs + (size_t)NN * 3 * HWSZ;
    float* z   = os + (size_t)NN * HWSZ;
    float* iz  = z + NN * 6;

    if (ws_size >= (size_t)HWSZ * sizeof(uint2)) {
        uint2* xp = (uint2*)d_ws;
        pack_kernel<<<HWSZ / 4 / 256, 256, 0, stream>>>(x, xp);
        dim3 grid(WW / 32, HH / 32, NN);
        warp_tile_kernel<<<grid, 256, 0, stream>>>(xp, theta, xs, os);
    } else {
        int total = NN * HWSZ;
        warp_kernel<<<(total + 255) / 256, 256, 0, stream>>>(x, theta, xs, os);
    }
    tail_kernel<<<1, 64, 0, stream>>>(theta, z, iz);
}